// Round 1
// 295.866 us; speedup vs baseline: 1.0197x; 1.0197x over previous
//
#include <hip/hip_runtime.h>
#include <math.h>

typedef _Float16 f16x8 __attribute__((ext_vector_type(8)));
typedef _Float16 f16x2 __attribute__((ext_vector_type(2)));
typedef float    f32x4 __attribute__((ext_vector_type(4)));

constexpr int kT    = 512;   // sequence length
constexpr int kH    = 16;    // hidden
constexpr int kL    = 8;     // layers
constexpr int kG    = 64;    // gates
constexpr int kNB   = 8;     // batch per block
constexpr int kPad  = 24;    // f16 row stride (48 B)
constexpr int kRows = 9;     // 8 batch rows + permanent zero row
constexpr int kSlots= 16;    // ring depth
constexpr int kLyr  = kL + 1;               // lyr 0 = x, lyr 1+l = layer l h
constexpr int kSE   = kLyr * kRows * kPad;  // f16 elems per slot (1944)
constexpr int kIters= 33;    // 528 wall steps >= last useful wall 525

constexpr float kL2E = 1.4426950408889634f;

__device__ __forceinline__ float ex2(float w)  { return __builtin_amdgcn_exp2f(w); }
__device__ __forceinline__ float rcp1p(float e){ return __builtin_amdgcn_rcpf(1.0f + e); }

// Round-9: barrier-lockstep wavefront pipeline (skew 2 per layer) + bpermute B2.
//  - layer l computes its timestep t = w - 2l at wall-step w
//  - writer slot (w+1)&15, reader slot w&15  -> write is 1 barrier ahead of read
//  - one s_barrier per wall step (lgkmcnt-only drain; vmcnt stays in flight
//    so wave 0's x prefetch crosses barriers)
//  - B2 fragment built from own just-computed h via 4x ds_bpermute_b32
//    (src lane = 16*j + 8*(q&1) + bn), zero-masked for !bact lanes
//  - no counters, no s_sleep, no volatile LDS polling
__global__ __launch_bounds__(512, 2)
void lstm_bar(const float* __restrict__ x,
              const float* __restrict__ Wih, const float* __restrict__ Whh,
              const float* __restrict__ bih, const float* __restrict__ bhh,
              const float* __restrict__ Wp,  const float* __restrict__ bpos,
              const float* __restrict__ Wo,  const float* __restrict__ bori,
              float* __restrict__ out)
{
    const int tid  = threadIdx.x;
    const int l    = tid >> 6;
    const int lane = tid & 63;
    const int n    = lane & 15;
    const int q    = lane >> 4;
    const int bn   = n & 7;
    const bool bact = ((q >> 1) == (n >> 3));

    __shared__ __align__(16) _Float16 hb[kSlots][kLyr][kRows][kPad];  // 62208 B

    {   // zero-init LDS
        int* hz = (int*)&hb[0][0][0][0];
        for (int i = tid; i < (int)(sizeof(hb) / 4); i += 512) hz[i] = 0;
    }
    __syncthreads();

    // ---- A fragments, scaled + column-permuted ----
    const float asc = ((n & 3) == 2) ? (-2.0f * kL2E) : (-kL2E);
    auto loadA = [&](const float* W, int T) -> f16x8 {
        const int wrow = (n & 3) * 16 + (n >> 2) + 4 * (q >> 1) + 8 * T;
        const float* src = W + (size_t)l * kG * kH + wrow * kH;
        f16x8 a;
        #pragma unroll
        for (int j = 0; j < 8; ++j) {
            const int u = (q & 1) * 4 + (j >> 1) + 8 * (j & 1);
            a[j] = (_Float16)(asc * src[u]);
        }
        return a;
    };
    const f16x8 A1T0 = loadA(Wih, 0), A2T0 = loadA(Whh, 0);
    const f16x8 A1T1 = loadA(Wih, 1), A2T1 = loadA(Whh, 1);

    // ---- scaled bias as MFMA C-init ----
    const int u0 = q + 4 * (n >> 3);
    f32x4 bias0, bias1;
    #pragma unroll
    for (int r = 0; r < 4; ++r) {
        const float sc = (r == 2) ? (-2.0f * kL2E) : (-kL2E);
        const int g0 = l * kG + r * 16 + u0;
        bias0[r] = sc * (bih[g0] + bhh[g0]);
        bias1[r] = sc * (bih[g0 + 8] + bhh[g0 + 8]);
    }

    // ---- LDS pointers ----
    const int boff = (bact ? bn * kPad : 8 * kPad) + (q & 1) * 8;
    const _Float16* b1b = &hb[0][l][0][0] + boff;          // v-input (x / h_{l-1})
    _Float16* hw = &hb[0][l + 1][bn][2 * u0];              // packed h (b32)
    _Float16* xw = &hb[0][0][lane >> 3][2 * (lane & 7)];   // packed x (b32)

    // ---- bpermute addressing: word jj of own B2 row comes from lane
    //      16*jj + 8*(q&1) + bn ; !bact lanes must contribute zeros ----
    const int bpbase = 4 * bn + 32 * (q & 1);
    const int mska   = bact ? -1 : 0;

    // ---- x staging (wave 0): slot k holds x(k+1); prime slots 15,0,1 with
    //      x(0),x(1),x(2); regs hold x(3),x(4) (prefetch distance 2) ----
    const int xa = lane & 7;
    const float* xg_ptr =
        x + ((size_t)(blockIdx.x * kNB + (lane >> 3)) * kT) * kH;
    float xa0 = 0.f, xa1 = 0.f, xb0 = 0.f, xb1 = 0.f;
    if (l == 0) {
        #pragma unroll
        for (int t = 0; t < 3; ++t) {
            f16x2 xp = { (_Float16)xg_ptr[t * kH + xa],
                         (_Float16)xg_ptr[t * kH + xa + 8] };
            *(f16x2*)(xw + ((t + 15) & 15) * kSE) = xp;
        }
        xa0 = xg_ptr[3 * kH + xa]; xa1 = xg_ptr[3 * kH + xa + 8];
        xb0 = xg_ptr[4 * kH + xa]; xb1 = xg_ptr[4 * kH + xa + 8];
    }
    __syncthreads();

    // ---- prime: dIn(t=0) from slot 15 (x(0) for l=0, zeros for l>0) ----
    const f16x8 B1p = *(const f16x8*)(b1b + 15 * kSE);
    f32x4 dIn0 = __builtin_amdgcn_mfma_f32_16x16x32_f16(A1T0, B1p, bias0, 0, 0, 0);
    f32x4 dIn1 = __builtin_amdgcn_mfma_f32_16x16x32_f16(A1T1, B1p, bias1, 0, 0, 0);

    f16x8 B2r;
    #pragma unroll
    for (int j = 0; j < 8; ++j) B2r[j] = (_Float16)0.f;

    float c0 = 0.f, c1 = 0.f;     // scaled cell state c' = -2*L2E*c
    const int tl = 2 * l;

    #pragma unroll 1
    for (int it = 0; it < kIters; ++it) {
        const int wb = it * 16;
        #pragma unroll
        for (int k = 0; k < 16; ++k) {
            const int w = wb + k;
            const int slotR = k * kSE;
            const int slotW = ((k + 1) & 15) * kSE;
            const int slotX = ((k + 2) & 15) * kSE;
            const bool active = ((unsigned)(w - tl) < (unsigned)kT);

            // B1(next) early: written by upstream at wall w-1, fenced by the
            // barrier that ended wall w-1; consumed by dIn MFMAs at body end
            const f16x8 B1n = *(const f16x8*)(b1b + slotR);

            // recurrent half: d = A2*h(t-1) + dIn(t)  [chain head]
            f32x4 d0 = __builtin_amdgcn_mfma_f32_16x16x32_f16(A2T0, B2r, dIn0, 0, 0, 0);
            f32x4 d1 = __builtin_amdgcn_mfma_f32_16x16x32_f16(A2T1, B2r, dIn1, 0, 0, 0);

            // in-lane cell update (args already scaled+biased)
            float h0, h1;
            {
                const float si = rcp1p(ex2(d0[0]));
                const float sf = rcp1p(ex2(d0[1]));
                const float sg = rcp1p(ex2(d0[2]));
                const float so = rcp1p(ex2(d0[3]));
                const float tgp = fmaf(-4.0f * kL2E, sg, 2.0f * kL2E);
                float cn = fmaf(sf, c0, si * tgp);
                cn = active ? cn : 0.0f;
                c0 = cn;
                h0 = so * fmaf(2.0f, rcp1p(ex2(cn)), -1.0f);
            }
            {
                const float si = rcp1p(ex2(d1[0]));
                const float sf = rcp1p(ex2(d1[1]));
                const float sg = rcp1p(ex2(d1[2]));
                const float so = rcp1p(ex2(d1[3]));
                const float tgp = fmaf(-4.0f * kL2E, sg, 2.0f * kL2E);
                float cn = fmaf(sf, c1, si * tgp);
                cn = active ? cn : 0.0f;
                c1 = cn;
                h1 = so * fmaf(2.0f, rcp1p(ex2(cn)), -1.0f);
            }

            // pack h; B2(next) via in-wave crossbar (no LDS round trip)
            f16x2 hp = { (_Float16)h0, (_Float16)h1 };
            union { f16x2 h; int i; } uh; uh.h = hp;
            const int hpi = uh.i;
            const int w0 = __builtin_amdgcn_ds_bpermute(bpbase      , hpi) & mska;
            const int w1 = __builtin_amdgcn_ds_bpermute(bpbase + 64 , hpi) & mska;
            const int w2 = __builtin_amdgcn_ds_bpermute(bpbase + 128, hpi) & mska;
            const int w3 = __builtin_amdgcn_ds_bpermute(bpbase + 192, hpi) & mska;

            // publish h(t) -> slot w+1 (for downstream layer + head)
            *(f16x2*)(hw + slotW) = hp;

            union { int i[4]; f16x8 v; } ub;
            ub.i[0] = w0; ub.i[1] = w1; ub.i[2] = w2; ub.i[3] = w3;
            B2r = ub.v;

            if (l == 0) {                            // publish x(w+3), prefetch
                f16x2 xp = { (_Float16)xa0, (_Float16)xa1 };
                *(f16x2*)(xw + slotX) = xp;
                xa0 = xb0; xa1 = xb1;
                int tn = w + 5; if (tn > kT - 1) tn = kT - 1;
                xb0 = xg_ptr[(size_t)tn * kH + xa];
                xb1 = xg_ptr[(size_t)tn * kH + xa + 8];
            }

            // input half for next wall step (off-chain), bias rides C
            dIn0 = __builtin_amdgcn_mfma_f32_16x16x32_f16(A1T0, B1n, bias0, 0, 0, 0);
            dIn1 = __builtin_amdgcn_mfma_f32_16x16x32_f16(A1T1, B1n, bias1, 0, 0, 0);

            // end of wall step: drain DS (h/x writes + bpermutes), barrier.
            // vmcnt intentionally NOT drained (x prefetch spans barriers).
            asm volatile("s_waitcnt lgkmcnt(0)\n\ts_barrier" ::: "memory");
        }
    }

    __syncthreads();

    // ---- head: layer-7 h(511) written at wall 525 -> slot (525+1)&15 = 14 ----
    if (l == kL - 1) {
        const int bb = lane >> 3;
        const int r  = lane & 7;
        if (r < 6) {
            const bool  isP   = (r < 3);
            const float* wrow = isP ? (Wp + r * kH) : (Wo + (r - 3) * kH);
            float acc = isP ? bpos[r] : bori[r - 3];
            #pragma unroll
            for (int u = 0; u < kH; ++u) {
                const int p = 2 * (u & 7) + (u >> 3);
                acc = fmaf((float)hb[14][kL][bb][p], wrow[u], acc);
            }
            if (!isP) acc = fmaf(2.0f, rcp1p(ex2(-2.0f * kL2E * acc)), -1.0f);
            out[(size_t)(blockIdx.x * kNB + bb) * 6 + r] = acc;
        }
    }
}

extern "C" void kernel_launch(void* const* d_in, const int* in_sizes, int n_in,
                              void* d_out, int out_size, void* d_ws, size_t ws_size,
                              hipStream_t stream) {
    const float* x    = (const float*)d_in[0];
    const float* Wih  = (const float*)d_in[1];
    const float* Whh  = (const float*)d_in[2];
    const float* bih  = (const float*)d_in[3];
    const float* bhh  = (const float*)d_in[4];
    const float* Wp   = (const float*)d_in[5];
    const float* bpos = (const float*)d_in[6];
    const float* Wo   = (const float*)d_in[7];
    const float* bori = (const float*)d_in[8];
    float* out = (float*)d_out;

    const int B = in_sizes[0] / (kT * kH);   // 2048
    lstm_bar<<<dim3(B / kNB), dim3(512), 0, stream>>>(x, Wih, Whh, bih, bhh,
                                                      Wp, bpos, Wo, bori, out);
}

// Round 2
// 280.098 us; speedup vs baseline: 1.0771x; 1.0563x over previous
//
#include <hip/hip_runtime.h>
#include <math.h>

typedef _Float16 f16x8 __attribute__((ext_vector_type(8)));
typedef float    f32x4 __attribute__((ext_vector_type(4)));

constexpr int kT    = 512;   // sequence length
constexpr int kH    = 16;    // hidden
constexpr int kL    = 8;     // layers
constexpr int kG    = 64;    // gates
constexpr int kNB   = 8;     // batch per block
constexpr int kPad  = 24;    // f16 row stride (48 B)
constexpr int kRows = 9;     // 8 batch rows + permanent zero row
constexpr int kSlots= 16;    // ring depth
constexpr int kLyr  = kL + 1;               // lyr 0 = x, lyr 1+l = layer l h
constexpr int kSE   = kLyr * kRows * kPad;  // f16 elems per slot (1944)
constexpr int kIters= 33;    // 528 wall steps >= last useful wall 525

constexpr float kL2E = 1.4426950408889634f;

__device__ __forceinline__ float ex2(float w)  { return __builtin_amdgcn_exp2f(w); }
__device__ __forceinline__ float rcp1p(float e){ return __builtin_amdgcn_rcpf(1.0f + e); }

// Round-10: 16-wave split (one wave per layer x MFMA-tile).
//  - wave wv: layer l = wv>>1, tile T = wv&1; lane owns ONE (batch,unit)
//    -> 10 transcendentals per wave-step (was 20), 4 waves/SIMD fill issue gaps
//  - plain (non-interleaved) h layout pos=u; h published as scalar b16 store
//  - B2 = own h(t-1) via b128 LDS read of slot w&15 (barrier-fenced)
//  - A/B column mapping simplifies to u = (q&1)*8 + j on both sides
//  - barrier lockstep (skew 2 per layer), lgkmcnt-only drain per wall step
__global__ __launch_bounds__(1024, 4)
void lstm_w16(const float* __restrict__ x,
              const float* __restrict__ Wih, const float* __restrict__ Whh,
              const float* __restrict__ bih, const float* __restrict__ bhh,
              const float* __restrict__ Wp,  const float* __restrict__ bpos,
              const float* __restrict__ Wo,  const float* __restrict__ bori,
              float* __restrict__ out)
{
    const int tid  = threadIdx.x;
    const int wv   = tid >> 6;
    const int l    = wv >> 1;
    const int T    = wv & 1;
    const int lane = tid & 63;
    const int n    = lane & 15;
    const int q    = lane >> 4;
    const int bn   = n & 7;
    const bool bact = ((q >> 1) == (n >> 3));

    __shared__ __align__(16) _Float16 hb[kSlots][kLyr][kRows][kPad];  // 62208 B

    {   // zero-init LDS
        int* hz = (int*)&hb[0][0][0][0];
        for (int i = tid; i < (int)(sizeof(hb) / 4); i += 1024) hz[i] = 0;
    }
    __syncthreads();

    // ---- A fragments, scaled; plain-layout column map u = (q&1)*8 + j ----
    // A row m=n: W row = (n&3)*16 + (n>>2) + 4*(q>>1) + 8T
    // scale: gate (n&3)==2 (g) -> -2*L2E else -L2E
    const float asc = ((n & 3) == 2) ? (-2.0f * kL2E) : (-kL2E);
    auto loadA = [&](const float* W) -> f16x8 {
        const int wrow = (n & 3) * 16 + (n >> 2) + 4 * (q >> 1) + 8 * T;
        const float* src = W + (size_t)l * kG * kH + wrow * kH;
        f16x8 a;
        #pragma unroll
        for (int j = 0; j < 8; ++j)
            a[j] = (_Float16)(asc * src[(q & 1) * 8 + j]);
        return a;
    };
    const f16x8 A1 = loadA(Wih);
    const f16x8 A2 = loadA(Whh);

    // ---- scaled bias as MFMA C-init: reg r = gate r, unit q+4*(n>>3)+8T ----
    const int u0 = q + 4 * (n >> 3) + 8 * T;    // this lane's single unit
    f32x4 bias;
    #pragma unroll
    for (int r = 0; r < 4; ++r) {
        const float sc = (r == 2) ? (-2.0f * kL2E) : (-kL2E);
        const int g0 = l * kG + r * 16 + u0;
        bias[r] = sc * (bih[g0] + bhh[g0]);
    }

    // ---- LDS pointers (plain layout) ----
    const int boff = (bact ? bn * kPad : 8 * kPad) + (q & 1) * 8;
    const _Float16* b1b = &hb[0][l    ][0][0] + boff;   // v-input (x / h_{l-1})
    const _Float16* b2b = &hb[0][l + 1][0][0] + boff;   // own h
    _Float16* hw = &hb[0][l + 1][bn][u0];               // h publish (b16)

    // ---- x staging (layer-0 wave pair): lane covers batch lane>>3, unit xu
    //      slot k holds x(k+1); prime slots 15,0,1 with x(0..2);
    //      regs xa,xb,xc hold x(3),x(4),x(5) (2-wall load-to-use distance) ----
    const int xu = (lane & 7) + 8 * T;
    _Float16* xw = &hb[0][0][lane >> 3][xu];
    const float* xg_ptr =
        x + ((size_t)(blockIdx.x * kNB + (lane >> 3)) * kT) * kH;
    float xa = 0.f, xb = 0.f, xc = 0.f;
    if (l == 0) {
        #pragma unroll
        for (int t = 0; t < 3; ++t)
            *(xw + ((t + 15) & 15) * kSE) = (_Float16)xg_ptr[t * kH + xu];
        xa = xg_ptr[3 * kH + xu];
        xb = xg_ptr[4 * kH + xu];
        xc = xg_ptr[5 * kH + xu];
    }
    __syncthreads();

    // ---- prime: dIn(t=0) from slot 15 (x(0) for l=0, zeros for l>0) ----
    const f16x8 B1p = *(const f16x8*)(b1b + 15 * kSE);
    f32x4 dIn = __builtin_amdgcn_mfma_f32_16x16x32_f16(A1, B1p, bias, 0, 0, 0);

    float c0 = 0.f;               // scaled cell state c' = -2*L2E*c
    const int tl = 2 * l;

    #pragma unroll 1
    for (int it = 0; it < kIters; ++it) {
        const int sb = it * 16;
        #pragma unroll
        for (int k = 0; k < 16; ++k) {
            const int s = sb + k;
            const int slotR = k * kSE;
            const int slotW = ((k + 1) & 15) * kSE;
            const int slotX = ((k + 2) & 15) * kSE;
            const bool active = ((unsigned)(s - tl) < (unsigned)kT);

            // B2 = own h(t-1), written wall s-1 -> slot s&15 (barrier-fenced)
            const f16x8 B2r = *(const f16x8*)(b2b + slotR);
            // B1(next) early: upstream h / x, consumed by dIn MFMA at body end
            const f16x8 B1n = *(const f16x8*)(b1b + slotR);

            // recurrent half: d = A2*h(t-1) + dIn(t)  [chain head]
            f32x4 d = __builtin_amdgcn_mfma_f32_16x16x32_f16(A2, B2r, dIn, 0, 0, 0);

            // in-lane cell update, single (batch,unit); args scaled+biased
            const float si = rcp1p(ex2(d[0]));
            const float sf = rcp1p(ex2(d[1]));
            const float sg = rcp1p(ex2(d[2]));
            const float so = rcp1p(ex2(d[3]));
            const float tgp = fmaf(-4.0f * kL2E, sg, 2.0f * kL2E);
            float cn = fmaf(sf, c0, si * tgp);
            cn = active ? cn : 0.0f;
            c0 = cn;
            const float h0 = so * fmaf(2.0f, rcp1p(ex2(cn)), -1.0f);

            // publish h(t) -> slot s+1 (own recurrence + downstream + head)
            *(hw + slotW) = (_Float16)h0;

            if (l == 0) {                    // publish x(s+3), rotate prefetch
                *(xw + slotX) = (_Float16)xa;
                xa = xb; xb = xc;
                int tn = s + 6; if (tn > kT - 1) tn = kT - 1;
                xc = xg_ptr[(size_t)tn * kH + xu];
            }

            // input half for next wall step (off-chain), bias rides C
            dIn = __builtin_amdgcn_mfma_f32_16x16x32_f16(A1, B1n, bias, 0, 0, 0);

            // end of wall step: drain DS (h/x writes), barrier.
            // vmcnt intentionally NOT drained (x prefetch spans barriers).
            asm volatile("s_waitcnt lgkmcnt(0)\n\ts_barrier" ::: "memory");
        }
    }

    __syncthreads();

    // ---- head: layer-7 h(511) written at wall 525 -> slot (525+1)&15 = 14 ----
    if (wv == 15) {
        const int bb = lane >> 3;
        const int r  = lane & 7;
        if (r < 6) {
            const bool  isP   = (r < 3);
            const float* wrow = isP ? (Wp + r * kH) : (Wo + (r - 3) * kH);
            float acc = isP ? bpos[r] : bori[r - 3];
            #pragma unroll
            for (int u = 0; u < kH; ++u)
                acc = fmaf((float)hb[14][kL][bb][u], wrow[u], acc);
            if (!isP) acc = fmaf(2.0f, rcp1p(ex2(-2.0f * kL2E * acc)), -1.0f);
            out[(size_t)(blockIdx.x * kNB + bb) * 6 + r] = acc;
        }
    }
}

extern "C" void kernel_launch(void* const* d_in, const int* in_sizes, int n_in,
                              void* d_out, int out_size, void* d_ws, size_t ws_size,
                              hipStream_t stream) {
    const float* x    = (const float*)d_in[0];
    const float* Wih  = (const float*)d_in[1];
    const float* Whh  = (const float*)d_in[2];
    const float* bih  = (const float*)d_in[3];
    const float* bhh  = (const float*)d_in[4];
    const float* Wp   = (const float*)d_in[5];
    const float* bpos = (const float*)d_in[6];
    const float* Wo   = (const float*)d_in[7];
    const float* bori = (const float*)d_in[8];
    float* out = (float*)d_out;

    const int B = in_sizes[0] / (kT * kH);   // 2048
    lstm_w16<<<dim3(B / kNB), dim3(1024), 0, stream>>>(x, Wih, Whh, bih, bhh,
                                                       Wp, bpos, Wo, bori, out);
}